// Round 1
// baseline (304.563 us; speedup 1.0000x reference)
//
#include <hip/hip_runtime.h>

// RelatEntAtt: E=4096 entities, R=64 relations, D=256 dims.
// Fully fused, recompute-based: the (E,R,D) 'att' tensor is never materialized.
// All softmaxes done WITHOUT max-subtraction (values bounded: |att| <~ 20,
// sums <~ 2e12, safe in fp32), using exp2 with log2(e) folded into the
// adj-softmax output (leaky commutes with positive scale).

#define EN 4096
#define RN 64
#define DN 256
#define LOG2E 1.44269504088896340736f
#define CHA 8   // e's per block in kA  -> grid 512
#define CHB 8   // e's per block in kB  -> grid 512

__device__ __forceinline__ float ex2(float x){ return __builtin_amdgcn_exp2f(x); }

// DPP row16 prefix-sum step: v += (lane-N within row16, 0 if out of row)
template<int CTRL>
__device__ __forceinline__ float dpp_add(float v){
  int m = __builtin_amdgcn_update_dpp(0, __float_as_int(v), CTRL, 0xf, 0xf, true);
  return v + __int_as_float(m);
}
// After this, lane (i%16)==15 holds the sum of its 16-lane row.
__device__ __forceinline__ float row16_sum(float v){
  v = dpp_add<0x111>(v); // row_shr:1
  v = dpp_add<0x112>(v); // row_shr:2
  v = dpp_add<0x114>(v); // row_shr:4
  v = dpp_add<0x118>(v); // row_shr:8
  return v;
}

// ---- kernel 1: s2[e,j] = softmax_j(adj[e,:]) * LOG2E ----
__global__ __launch_bounds__(256) void k_adj(const float* __restrict__ adj,
                                             float* __restrict__ s2){
  const int lane = threadIdx.x & 63;
  const int e = blockIdx.x*4 + (threadIdx.x >> 6);
  float a = adj[e*RN + lane];
  float ev = ex2(a * LOG2E);
  float s = ev;
  #pragma unroll
  for(int off = 32; off > 0; off >>= 1) s += __shfl_xor(s, off, 64);
  s2[e*RN + lane] = ev * (LOG2E / s);
}

// ---- kernel A: per (e,d): lR = sum_j exp2(att2) -> invlR; lE[j,d] += exp2 ----
__global__ __launch_bounds__(256,2) void kA(const float* __restrict__ h,
                                            const float* __restrict__ r,
                                            const float* __restrict__ s2,
                                            float* __restrict__ invlR,
                                            float* __restrict__ lE){
  const int d = threadIdx.x;
  float rcol[RN], lEacc[RN];
  #pragma unroll
  for(int j = 0; j < RN; j++){ rcol[j] = r[j*DN + d]; lEacc[j] = 0.f; }
  const int e0 = blockIdx.x * CHA;
  for(int ee = 0; ee < CHA; ++ee){
    const int e = e0 + ee;
    const float he = h[e*DN + d];
    const float* __restrict__ srow = s2 + e*RN;
    float lR = 0.f;
    #pragma unroll
    for(int j = 0; j < RN; j++){
      float t  = srow[j] * he * rcol[j];
      float ev = ex2(fmaxf(t, 0.2f*t));   // leaky (scale>0 commutes)
      lR += ev;
      lEacc[j] += ev;
    }
    invlR[e*DN + d] = 1.0f / lR;
  }
  #pragma unroll
  for(int j = 0; j < RN; j++) atomicAdd(&lE[j*DN + d], lEacc[j]);
}

// ---- kernel B: main fused sweep ----
// per (e,d): pR = ex*invlR (att_R), pE = ex*invlE (att_E)
//   h'[e,d]  = h * sum_j pE          (direct coalesced store, elu)
//   r'[j,d] += pR                    (64-reg acc over e-chunk, atomic flush)
//   alpha_logit[e,j] = sum_d pR*W_d  (row16 DPP + LDS partials)
__global__ __launch_bounds__(256,2) void kB(const float* __restrict__ h,
                                            const float* __restrict__ r,
                                            const float* __restrict__ s2,
                                            const float* __restrict__ invlR,
                                            const float* __restrict__ lE,
                                            const float* __restrict__ W,
                                            float* __restrict__ hout,
                                            float* __restrict__ alog,
                                            float* __restrict__ racc_g){
  const int tid  = threadIdx.x;        // = d
  const int lane = tid & 63;
  __shared__ float apart[16*68];       // 16 slots x 64 j, padded +4 (bank spread)
  float rcol[RN], ile[RN], rAcc[RN];
  #pragma unroll
  for(int j = 0; j < RN; j++){
    rcol[j] = r[j*DN + tid];
    ile[j]  = 1.0f / lE[j*DN + tid];
    rAcc[j] = 0.f;
  }
  const float wd = W[tid];
  const int e0 = blockIdx.x * CHB;
  for(int ee = 0; ee < CHB; ++ee){
    const int e = e0 + ee;
    const float he = h[e*DN + tid];
    const float il = invlR[e*DN + tid];
    const float* __restrict__ srow = s2 + e*RN;
    float sE = 0.f;
    #pragma unroll
    for(int jg = 0; jg < 16; jg++){
      float4 st;
      #pragma unroll
      for(int jj = 0; jj < 4; jj++){
        const int j = jg*4 + jj;
        float t  = srow[j] * he * rcol[j];
        float ev = ex2(fmaxf(t, 0.2f*t));
        float pR = ev * il;
        rAcc[j] += pR;
        sE = fmaf(ev, ile[j], sE);
        float rs = row16_sum(pR * wd);
        if(jj==0) st.x = rs; else if(jj==1) st.y = rs;
        else if(jj==2) st.z = rs; else st.w = rs;
      }
      if((lane & 15) == 15){
        *reinterpret_cast<float4*>(&apart[(tid>>4)*68 + jg*4]) = st;
      }
    }
    float hp = he * sE;
    hout[e*DN + tid] = hp > 0.f ? hp : (ex2(hp*LOG2E) - 1.0f);
    __syncthreads();
    if(tid < RN){
      float sum = 0.f;
      #pragma unroll
      for(int sl = 0; sl < 16; sl++) sum += apart[sl*68 + tid];
      alog[e*RN + tid] = sum;
    }
    __syncthreads();
  }
  #pragma unroll
  for(int j = 0; j < RN; j++) atomicAdd(&racc_g[j*DN + tid], rAcc[j]);
}

// ---- kernel R: r' = elu(r * racc) ----
__global__ __launch_bounds__(256) void kR(const float* __restrict__ r,
                                          const float* __restrict__ racc,
                                          float* __restrict__ rout){
  int i = blockIdx.x*256 + threadIdx.x;
  float v = r[i] * racc[i];
  rout[i] = v > 0.f ? v : (ex2(v*LOG2E) - 1.0f);
}

// ---- kernel Alpha: softmax over each contiguous 4096-chunk of alog ----
// (the reference's reshape(R,E,1)+softmax(axis=1) is exactly this on the
//  flat e*64+j logit array; b_lin is softmax-shift-invariant and dropped)
__global__ __launch_bounds__(256) void kAlpha(const float* __restrict__ alog,
                                              float* __restrict__ aout){
  const int rr = blockIdx.x, tid = threadIdx.x;
  const float* __restrict__ row = alog + rr*EN;
  float exv[16]; float s = 0.f;
  #pragma unroll
  for(int k = 0; k < 16; k++){
    float v = ex2(row[k*256 + tid] * LOG2E);
    exv[k] = v; s += v;
  }
  #pragma unroll
  for(int off = 32; off > 0; off >>= 1) s += __shfl_xor(s, off, 64);
  __shared__ float wsum[4];
  if((tid & 63) == 0) wsum[tid>>6] = s;
  __syncthreads();
  float inv = 1.0f / (wsum[0] + wsum[1] + wsum[2] + wsum[3]);
  float* __restrict__ orow = aout + rr*EN;
  #pragma unroll
  for(int k = 0; k < 16; k++) orow[k*256 + tid] = exv[k] * inv;
}

extern "C" void kernel_launch(void* const* d_in, const int* in_sizes, int n_in,
                              void* d_out, int out_size, void* d_ws, size_t ws_size,
                              hipStream_t stream){
  (void)in_sizes; (void)n_in; (void)out_size; (void)ws_size;
  const float* h   = (const float*)d_in[0];
  const float* r   = (const float*)d_in[1];
  const float* adj = (const float*)d_in[2];
  const float* W   = (const float*)d_in[3];
  // d_in[4] = b_lin: unused (softmax shift invariance)

  float* ws    = (float*)d_ws;
  float* s2    = ws;                 // EN*RN   = 262144 floats
  float* invlR = s2 + EN*RN;         // EN*DN   = 1048576
  float* lE    = invlR + EN*DN;      // RN*DN   = 16384
  float* racc  = lE + RN*DN;         // RN*DN   = 16384
  float* alog  = racc + RN*DN;       // EN*RN   = 262144  (total ~6.4 MB)

  float* hout = (float*)d_out;           // EN*DN
  float* rout = hout + EN*DN;            // RN*DN
  float* aout = rout + RN*DN;            // RN*EN

  hipMemsetAsync(lE, 0, size_t(RN*DN*2)*sizeof(float), stream); // lE + racc

  k_adj <<<EN/4,    256, 0, stream>>>(adj, s2);
  kA    <<<EN/CHA,  256, 0, stream>>>(h, r, s2, invlR, lE);
  kB    <<<EN/CHB,  256, 0, stream>>>(h, r, s2, invlR, lE, W, hout, alog, racc);
  kR    <<<RN*DN/256, 256, 0, stream>>>(r, racc, rout);
  kAlpha<<<RN,      256, 0, stream>>>(alog, aout);
}

// Round 2
// 180.924 us; speedup vs baseline: 1.6834x; 1.6834x over previous
//
#include <hip/hip_runtime.h>

// RelatEntAtt: E=4096, R=64, D=256. Fully fused recompute; att (E,R,D) never
// materialized. No max-subtraction needed (|att| <~ 20, sums <~ 2e12, fp32-safe);
// exp2 with log2(e) folded into the adj-softmax output (leaky commutes with
// positive scale). R2: j tiled in 16s so private arrays SROA-promote to regs
// (R1's 64-elem arrays went to scratch: 176 MB spill traffic, VALUBusy 14%).

#define EN 4096
#define RN 64
#define DN 256
#define JT 16          // j-tile width (SROA-friendly)
#define NJT (RN/JT)    // 4 tiles
#define LOG2E 1.44269504088896340736f
#define CHA 8   // e's per block in kA  -> grid 512
#define CHB 8   // e's per block in kB  -> grid 512

__device__ __forceinline__ float ex2(float x){ return __builtin_amdgcn_exp2f(x); }

template<int CTRL>
__device__ __forceinline__ float dpp_add(float v){
  int m = __builtin_amdgcn_update_dpp(0, __float_as_int(v), CTRL, 0xf, 0xf, true);
  return v + __int_as_float(m);
}
// lane (i%16)==15 ends with the sum of its 16-lane row
__device__ __forceinline__ float row16_sum(float v){
  v = dpp_add<0x111>(v);
  v = dpp_add<0x112>(v);
  v = dpp_add<0x114>(v);
  v = dpp_add<0x118>(v);
  return v;
}

// ---- s2[e,j] = softmax_j(adj[e,:]) * LOG2E ----
__global__ __launch_bounds__(256) void k_adj(const float* __restrict__ adj,
                                             float* __restrict__ s2){
  const int lane = threadIdx.x & 63;
  const int e = blockIdx.x*4 + (threadIdx.x >> 6);
  float a = adj[e*RN + lane];
  float ev = ex2(a * LOG2E);
  float s = ev;
  #pragma unroll
  for(int off = 32; off > 0; off >>= 1) s += __shfl_xor(s, off, 64);
  s2[e*RN + lane] = ev * (LOG2E / s);
}

// ---- kA: invlR[e,d] = 1/sum_j ev;  lE[j,d] += ev (atomics) ----
__global__ __launch_bounds__(256,4) void kA(const float* __restrict__ h,
                                            const float* __restrict__ r,
                                            const float* __restrict__ s2,
                                            float* __restrict__ invlR,
                                            float* __restrict__ lE){
  const int d = threadIdx.x;
  const int e0 = blockIdx.x * CHA;
  __shared__ float s2s[CHA*RN];            // 2 KB
  #pragma unroll
  for(int k = 0; k < CHA*RN/256; k++) s2s[k*256 + d] = s2[e0*RN + k*256 + d];
  __syncthreads();

  float lR[CHA];
  #pragma unroll
  for(int ee = 0; ee < CHA; ee++) lR[ee] = 0.f;

  #pragma unroll
  for(int jt = 0; jt < NJT; jt++){
    float rcol[JT], lEacc[JT];
    #pragma unroll
    for(int jj = 0; jj < JT; jj++){ rcol[jj] = r[(jt*JT+jj)*DN + d]; lEacc[jj] = 0.f; }
    #pragma unroll
    for(int ee = 0; ee < CHA; ee++){
      const float he = h[(e0+ee)*DN + d];
      #pragma unroll
      for(int jj = 0; jj < JT; jj++){
        float t  = s2s[ee*RN + jt*JT + jj] * he * rcol[jj];
        float ev = ex2(fmaxf(t, 0.2f*t));
        lR[ee]   += ev;
        lEacc[jj] += ev;
      }
    }
    #pragma unroll
    for(int jj = 0; jj < JT; jj++) atomicAdd(&lE[(jt*JT+jj)*DN + d], lEacc[jj]);
  }
  #pragma unroll
  for(int ee = 0; ee < CHA; ee++) invlR[(e0+ee)*DN + d] = 1.0f / lR[ee];
}

// ---- kB: main fused sweep ----
// per (e,d): pR = ev*invlR (att_R), pE = ev/lE (att_E)
//   h'[e,d]  = elu(h * sum_j pE)     coalesced store after tile loop
//   r'[j,d] += pR                    16-reg acc per tile, atomic flush
//   alog[e,j] = sum_d pR*W_d         row16 DPP + LDS partial combine
__global__ __launch_bounds__(256,4) void kB(const float* __restrict__ h,
                                            const float* __restrict__ r,
                                            const float* __restrict__ s2,
                                            const float* __restrict__ invlR,
                                            const float* __restrict__ lE,
                                            const float* __restrict__ W,
                                            float* __restrict__ hout,
                                            float* __restrict__ alog,
                                            float* __restrict__ racc_g){
  const int tid  = threadIdx.x;            // = d
  const int lane = tid & 63;
  const int grp  = tid >> 4;               // 16 groups of 16 lanes
  const int e0   = blockIdx.x * CHB;
  __shared__ float s2s[CHB*RN];            // 2 KB
  __shared__ float apart[CHB*16*20];       // [ee][g][jj], jj stride 1, g stride 20 -> 12.8 KB
  #pragma unroll
  for(int k = 0; k < CHB*RN/256; k++) s2s[k*256 + tid] = s2[e0*RN + k*256 + tid];
  __syncthreads();

  const float wd = W[tid];
  float sE[CHB];
  #pragma unroll
  for(int ee = 0; ee < CHB; ee++) sE[ee] = 0.f;

  #pragma unroll
  for(int jt = 0; jt < NJT; jt++){
    float rcol[JT], ile[JT], rAcc[JT];
    #pragma unroll
    for(int jj = 0; jj < JT; jj++){
      const int j = jt*JT + jj;
      rcol[jj] = r[j*DN + tid];
      ile[jj]  = 1.0f / lE[j*DN + tid];
      rAcc[jj] = 0.f;
    }
    for(int ee = 0; ee < CHB; ee++){
      const int e = e0 + ee;
      const float he = h[e*DN + tid];
      const float il = invlR[e*DN + tid];
      const float u  = il * wd;
      #pragma unroll
      for(int jg = 0; jg < JT/4; jg++){
        float4 st;
        #pragma unroll
        for(int jj4 = 0; jj4 < 4; jj4++){
          const int jj = jg*4 + jj4;
          float t  = s2s[ee*RN + jt*JT + jj] * he * rcol[jj];
          float ev = ex2(fmaxf(t, 0.2f*t));
          rAcc[jj] = fmaf(ev, il, rAcc[jj]);      // pR accumulated over e
          sE[ee]   = fmaf(ev, ile[jj], sE[ee]);   // pE sum over j
          float rs = row16_sum(ev * u);           // alog contribution
          if(jj4==0) st.x = rs; else if(jj4==1) st.y = rs;
          else if(jj4==2) st.z = rs; else st.w = rs;
        }
        if((lane & 15) == 15){
          *reinterpret_cast<float4*>(&apart[(ee*16 + grp)*20 + jg*4]) = st;
        }
      }
    }
    __syncthreads();
    if(tid < CHB*JT){                        // 128 threads: ee = tid>>4, jj = tid&15
      const int ee = tid >> 4, jj = tid & 15;
      float sum = 0.f;
      #pragma unroll
      for(int g = 0; g < 16; g++) sum += apart[(ee*16 + g)*20 + jj];
      alog[(e0+ee)*RN + jt*JT + jj] = sum;
    }
    __syncthreads();
    #pragma unroll
    for(int jj = 0; jj < JT; jj++) atomicAdd(&racc_g[(jt*JT+jj)*DN + tid], rAcc[jj]);
  }
  #pragma unroll
  for(int ee = 0; ee < CHB; ee++){
    const int e = e0 + ee;
    float hp = h[e*DN + tid] * sE[ee];       // h reload is L1-hot
    hout[e*DN + tid] = hp > 0.f ? hp : (ex2(hp*LOG2E) - 1.0f);
  }
}

// ---- r' = elu(r * racc) ----
__global__ __launch_bounds__(256) void kR(const float* __restrict__ r,
                                          const float* __restrict__ racc,
                                          float* __restrict__ rout){
  int i = blockIdx.x*256 + threadIdx.x;
  float v = r[i] * racc[i];
  rout[i] = v > 0.f ? v : (ex2(v*LOG2E) - 1.0f);
}

// ---- alpha: softmax over each contiguous 4096-chunk of flat alog ----
// (reference's reshape(R,E,1)+softmax(axis=1) == this on the e*64+j flat array;
//  b_lin dropped by shift invariance)
__global__ __launch_bounds__(256) void kAlpha(const float* __restrict__ alog,
                                              float* __restrict__ aout){
  const int rr = blockIdx.x, tid = threadIdx.x;
  const float* __restrict__ row = alog + rr*EN;
  float exv[16]; float s = 0.f;
  #pragma unroll
  for(int k = 0; k < 16; k++){
    float v = ex2(row[k*256 + tid] * LOG2E);
    exv[k] = v; s += v;
  }
  #pragma unroll
  for(int off = 32; off > 0; off >>= 1) s += __shfl_xor(s, off, 64);
  __shared__ float wsum[4];
  if((tid & 63) == 0) wsum[tid>>6] = s;
  __syncthreads();
  float inv = 1.0f / (wsum[0] + wsum[1] + wsum[2] + wsum[3]);
  float* __restrict__ orow = aout + rr*EN;
  #pragma unroll
  for(int k = 0; k < 16; k++) orow[k*256 + tid] = exv[k] * inv;
}

extern "C" void kernel_launch(void* const* d_in, const int* in_sizes, int n_in,
                              void* d_out, int out_size, void* d_ws, size_t ws_size,
                              hipStream_t stream){
  (void)in_sizes; (void)n_in; (void)out_size; (void)ws_size;
  const float* h   = (const float*)d_in[0];
  const float* r   = (const float*)d_in[1];
  const float* adj = (const float*)d_in[2];
  const float* W   = (const float*)d_in[3];
  // d_in[4] = b_lin: unused (softmax shift invariance)

  float* ws    = (float*)d_ws;
  float* s2    = ws;                 // EN*RN
  float* invlR = s2 + EN*RN;         // EN*DN
  float* lE    = invlR + EN*DN;      // RN*DN
  float* racc  = lE + RN*DN;         // RN*DN
  float* alog  = racc + RN*DN;       // EN*RN

  float* hout = (float*)d_out;           // EN*DN
  float* rout = hout + EN*DN;            // RN*DN
  float* aout = rout + RN*DN;            // RN*EN

  hipMemsetAsync(lE, 0, size_t(RN*DN*2)*sizeof(float), stream); // lE + racc

  k_adj <<<EN/4,      256, 0, stream>>>(adj, s2);
  kA    <<<EN/CHA,    256, 0, stream>>>(h, r, s2, invlR, lE);
  kB    <<<EN/CHB,    256, 0, stream>>>(h, r, s2, invlR, lE, W, hout, alog, racc);
  kR    <<<RN*DN/256, 256, 0, stream>>>(r, racc, rout);
  kAlpha<<<RN,        256, 0, stream>>>(alog, aout);
}